// Round 6
// baseline (341.851 us; speedup 1.0000x reference)
//
#include <hip/hip_runtime.h>
#include <cstddef>

#define N_NODES 50000
#define N_EDGES 1600000
#define N_ETOT  (N_EDGES + N_NODES)
#define F_IN    512
#define HEADS   8
#define HID     8
#define CLS     16

#define NBUCK   196      // ceil(50000/256) dst buckets
#define BCAP    12288    // per-bucket capacity
#define CHUNKA  4096     // edges per block in phase A

typedef float v4 __attribute__((ext_vector_type(4)));
typedef float v2 __attribute__((ext_vector_type(2)));
typedef unsigned short us4 __attribute__((ext_vector_type(4)));
typedef unsigned int u4 __attribute__((ext_vector_type(4)));
typedef short bfrag __attribute__((ext_vector_type(8)));   // 8 bf16 = 4 VGPRs
typedef float ffrag __attribute__((ext_vector_type(4)));   // MFMA acc

__device__ inline float b2f_lo(unsigned int u) { return __uint_as_float(u << 16); }
__device__ inline float b2f_hi(unsigned int u) { return __uint_as_float(u & 0xffff0000u); }
__device__ inline unsigned short f2b(float f) {
  unsigned int x = __float_as_uint(f);
  unsigned int r = (x + 0x7fffu + ((x >> 16) & 1u)) >> 16;   // RNE
  return (unsigned short)r;
}

// ---- W1 (512x64 fp32) -> W1bT (64x512 bf16); block 128 zeroes gcur ----------
__global__ __launch_bounds__(256) void w1t_kernel(
    const float* __restrict__ W, unsigned short* __restrict__ WT,
    int* __restrict__ gcur) {
  int t = threadIdx.x;
  if (blockIdx.x == 128) {
    if (t < NBUCK) gcur[t] = 0;
    return;
  }
  int i = blockIdx.x * 256 + t;
  int k = i >> 6, n = i & 63;
  WT[n * F_IN + k] = f2b(W[i]);
}

// ---- GEMM1 (MFMA): x(50000x512 fp32) @ W1 -> h1b(bf16) + attn logits ---------
__global__ __launch_bounds__(256) void gemm1_kernel(
    const float* __restrict__ x, const unsigned short* __restrict__ W1bT,
    const float* __restrict__ att_src, const float* __restrict__ att_dst,
    unsigned short* __restrict__ h1b, float* __restrict__ a_src,
    float* __restrict__ a_dst, int nrows) {
  __shared__ unsigned short xsb[64][72];
  __shared__ unsigned short wsb[64][72];
  int t = threadIdx.x;
  int lane = t & 63;
  int w = t >> 6;
  int row0 = blockIdx.x * 64;
  ffrag acc[4];
  acc[0] = 0.f; acc[1] = 0.f; acc[2] = 0.f; acc[3] = 0.f;

  int mrow = lane & 15;
  int koff = (lane >> 4) * 8;

  for (int kt = 0; kt < 8; ++kt) {
    int k0 = kt * 64;
#pragma unroll
    for (int r = 0; r < 4; ++r) {
      int slot = t + r * 256;
      int m = slot >> 4;
      int k4 = (slot & 15) * 4;
      v4 v = 0.f;
      int grow = row0 + m;
      if (grow < nrows) v = *(const v4*)(x + (size_t)grow * F_IN + k0 + k4);
      us4 o;
      o.x = f2b(v[0]); o.y = f2b(v[1]); o.z = f2b(v[2]); o.w = f2b(v[3]);
      *(us4*)&xsb[m][k4] = o;
    }
#pragma unroll
    for (int r = 0; r < 2; ++r) {
      int slot = t + r * 256;
      int nn = slot >> 3;
      int k8 = (slot & 7) * 8;
      *(bfrag*)&wsb[nn][k8] = *(const bfrag*)(W1bT + nn * F_IN + k0 + k8);
    }
    __syncthreads();
#pragma unroll
    for (int kk = 0; kk < 64; kk += 32) {
      bfrag a = *(const bfrag*)&xsb[w * 16 + mrow][kk + koff];
#pragma unroll
      for (int tt = 0; tt < 4; ++tt) {
        bfrag b = *(const bfrag*)&wsb[tt * 16 + mrow][kk + koff];
        acc[tt] = __builtin_amdgcn_mfma_f32_16x16x32_bf16(a, b, acc[tt], 0, 0, 0);
      }
    }
    __syncthreads();
  }
  int c = lane & 15, q = lane >> 4;
  float as_[4], ad_[4];
#pragma unroll
  for (int tt = 0; tt < 4; ++tt) {
    as_[tt] = att_src[tt * 16 + c];
    ad_[tt] = att_dst[tt * 16 + c];
  }
#pragma unroll
  for (int r = 0; r < 4; ++r) {
    int grow = row0 + w * 16 + q * 4 + r;
    float ps[4], pd[4];
#pragma unroll
    for (int tt = 0; tt < 4; ++tt) {
      ps[tt] = acc[tt][r] * as_[tt];
      pd[tt] = acc[tt][r] * ad_[tt];
    }
#pragma unroll
    for (int o = 1; o < 8; o <<= 1) {
#pragma unroll
      for (int tt = 0; tt < 4; ++tt) {
        ps[tt] += __shfl_xor(ps[tt], o);
        pd[tt] += __shfl_xor(pd[tt], o);
      }
    }
    if (grow < nrows) {
#pragma unroll
      for (int tt = 0; tt < 4; ++tt)
        h1b[(size_t)grow * 64 + tt * 16 + c] = f2b(acc[tt][r]);
      if ((c & 7) == 0) {
#pragma unroll
        for (int tt = 0; tt < 4; ++tt) {
          int head = tt * 2 + (c >> 3);
          a_src[grow * 8 + head] = ps[tt];
          a_dst[grow * 8 + head] = pd[tt];
        }
      }
    }
  }
}

// --------------------------- CSR build (bucketed, 2 kernels) -------------------
__global__ __launch_bounds__(256) void bucketA_kernel(
    const int* __restrict__ src_idx, const int* __restrict__ dst_idx,
    int* __restrict__ gcur, int* __restrict__ abuck) {
  __shared__ int hist[NBUCK];
  __shared__ int base[NBUCK];
  __shared__ int cur[NBUCK];
  int t = threadIdx.x;
  if (t < NBUCK) hist[t] = 0;
  __syncthreads();
  int e0 = blockIdx.x * CHUNKA;
  int eend = e0 + CHUNKA;
  if (eend > N_EDGES) eend = N_EDGES;
  for (int e = e0 + t; e < eend; e += 256)
    atomicAdd(&hist[(unsigned)dst_idx[e] >> 8], 1);
  __syncthreads();
  if (t < NBUCK) {
    int c = hist[t];
    base[t] = c ? atomicAdd(&gcur[t], c) : 0;
    cur[t] = 0;
  }
  __syncthreads();
  for (int e = e0 + t; e < eend; e += 256) {
    int s = src_idx[e];
    int d = dst_idx[e];
    int b = (unsigned)d >> 8;
    int r = atomicAdd(&cur[b], 1);
    abuck[b * BCAP + base[b] + r] = (s << 8) | (d & 255);
  }
}

// Phase B: per-bucket; scans gcur in-block for its base; 16-bit csr out
__global__ __launch_bounds__(256) void bucketB_kernel(
    const int* __restrict__ gcur, const int* __restrict__ abuck,
    int* __restrict__ indptr, unsigned short* __restrict__ csr16) {
  __shared__ int gs[256];
  __shared__ int hist[256];
  __shared__ int sm[256];
  __shared__ int cur[256];
  int b = blockIdx.x;
  int t = threadIdx.x;
  // scan gcur for bucket base
  int gv = (t < NBUCK) ? gcur[t] : 0;
  gs[t] = gv;
  __syncthreads();
  for (int o = 1; o < 256; o <<= 1) {
    int u = (t >= o) ? gs[t - o] : 0;
    __syncthreads();
    gs[t] += u;
    __syncthreads();
  }
  int bbase = (b > 0 ? gs[b - 1] : 0) + 256 * b;   // +self-loops of prior buckets
  int M = gcur[b];
  int node0 = b * 256;
  int nnodes = N_NODES - node0;
  if (nnodes > 256) nnodes = 256;
  hist[t] = (t < nnodes) ? 1 : 0;   // self-loop
  __syncthreads();
  const int* ab = abuck + b * BCAP;
  for (int i = t; i < M; i += 256)
    atomicAdd(&hist[ab[i] & 255], 1);
  __syncthreads();
  int v = hist[t];
  sm[t] = v;
  __syncthreads();
  for (int o = 1; o < 256; o <<= 1) {
    int u = (t >= o) ? sm[t - o] : 0;
    __syncthreads();
    sm[t] += u;
    __syncthreads();
  }
  int excl = sm[t] - v;
  cur[t] = excl;
  if (t < nnodes) indptr[node0 + t] = bbase + excl;
  if (b == NBUCK - 1 && t == 0) indptr[N_NODES] = N_ETOT;
  __syncthreads();
  for (int i = t; i < M; i += 256) {
    int entry = ab[i];
    int r = atomicAdd(&cur[entry & 255], 1);
    csr16[bbase + r] = (unsigned short)((unsigned)entry >> 8);
  }
  if (t < nnodes) {
    int r = atomicAdd(&cur[t], 1);
    csr16[bbase + r] = (unsigned short)(node0 + t);
  }
}

// ---- layer-1 softmax+aggregate FUSED with layer-2 linear + attn2 logits -------
// wave = one node; lane = (edge slot j = lane>>3, head h = lane&7)
__global__ __launch_bounds__(256) void agg1_kernel(
    const int* __restrict__ indptr, const unsigned short* __restrict__ csr16,
    const unsigned short* __restrict__ h1b, const float* __restrict__ a_src1,
    const float* __restrict__ a_dst1, const float* __restrict__ bias1,
    const float* __restrict__ W2, const float* __restrict__ att_src2,
    const float* __restrict__ att_dst2, unsigned short* __restrict__ h2b,
    float* __restrict__ a_src2, float* __restrict__ a_dst2, int n) {
  int wave = threadIdx.x >> 6;
  int lane = threadIdx.x & 63;
  int node = blockIdx.x * 4 + wave;
  if (node >= n) return;
  int j = lane >> 3;
  int h = lane & 7;
  float adst = a_dst1[(unsigned)(node * 8 + h)];
  int beg = indptr[node], end = indptr[node + 1];
  float acc0=0.f, acc1=0.f, acc2=0.f, acc3=0.f, acc4=0.f, acc5=0.f, acc6=0.f, acc7=0.f;
  float den = 0.f;
  for (int base = beg; base < end; base += 64) {
    int m = end - base;
    if (m > 64) m = 64;
    int sv = (lane < m) ? (int)csr16[base + lane] : 0;
    for (int p = 0; p < m; p += 8) {
      int s = __shfl(sv, p + j);
      bool act = (p + j) < m;
      float e = a_src1[(unsigned)(s * 8 + h)] + adst;
      e = (e > 0.f) ? e : 0.2f * e;
      float w = act ? __expf(e) : 0.f;
      den += w;
      u4 f = *(const u4*)(h1b + (unsigned)(s * 64 + h * 8));
      acc0 += w * b2f_lo(f.x); acc1 += w * b2f_hi(f.x);
      acc2 += w * b2f_lo(f.y); acc3 += w * b2f_hi(f.y);
      acc4 += w * b2f_lo(f.z); acc5 += w * b2f_hi(f.z);
      acc6 += w * b2f_lo(f.w); acc7 += w * b2f_hi(f.w);
    }
  }
#pragma unroll
  for (int o = 8; o < 64; o <<= 1) {
    den  += __shfl_xor(den, o);
    acc0 += __shfl_xor(acc0, o); acc1 += __shfl_xor(acc1, o);
    acc2 += __shfl_xor(acc2, o); acc3 += __shfl_xor(acc3, o);
    acc4 += __shfl_xor(acc4, o); acc5 += __shfl_xor(acc5, o);
    acc6 += __shfl_xor(acc6, o); acc7 += __shfl_xor(acc7, o);
  }
  // all lanes now hold totals for channels 8h..8h+7 (same across j)
  float inv = 1.f / den;
  v4 b0 = *(const v4*)(bias1 + h * 8);
  v4 b1 = *(const v4*)(bias1 + h * 8 + 4);
  float oc[8];
  oc[0] = acc0 * inv + b0[0]; oc[1] = acc1 * inv + b0[1];
  oc[2] = acc2 * inv + b0[2]; oc[3] = acc3 * inv + b0[3];
  oc[4] = acc4 * inv + b1[0]; oc[5] = acc5 * inv + b1[1];
  oc[6] = acc6 * inv + b1[2]; oc[7] = acc7 * inv + b1[3];
#pragma unroll
  for (int k = 0; k < 8; ++k)
    oc[k] = (oc[k] > 0.f) ? oc[k] : expm1f(oc[k]);   // ELU
  // layer-2 linear: lane (j,h) -> classes 2j,2j+1, channels 8h..8h+7
  float p0 = 0.f, p1 = 0.f;
  const float* w2row = W2 + h * 8 * 16 + 2 * j;
#pragma unroll
  for (int k = 0; k < 8; ++k) {
    v2 wv = *(const v2*)(w2row + k * 16);
    p0 += oc[k] * wv[0];
    p1 += oc[k] * wv[1];
  }
#pragma unroll
  for (int o = 1; o < 8; o <<= 1) {   // reduce over h
    p0 += __shfl_xor(p0, o);
    p1 += __shfl_xor(p1, o);
  }
  // attn2 logits
  float ps = p0 * att_src2[2 * j] + p1 * att_src2[2 * j + 1];
  float pd = p0 * att_dst2[2 * j] + p1 * att_dst2[2 * j + 1];
#pragma unroll
  for (int o = 8; o < 64; o <<= 1) {  // reduce over j
    ps += __shfl_xor(ps, o);
    pd += __shfl_xor(pd, o);
  }
  if (h == 0) {
    unsigned pack = (unsigned)f2b(p0) | ((unsigned)f2b(p1) << 16);
    *(unsigned*)(h2b + (unsigned)(node * 16 + 2 * j)) = pack;
  }
  if (lane == 0) { a_src2[node] = ps; a_dst2[node] = pd; }
}

// ------- layer-2 aggregate + bias + log_softmax --------------------------------
__global__ __launch_bounds__(256) void agg2_kernel(
    const int* __restrict__ indptr, const unsigned short* __restrict__ csr16,
    const unsigned short* __restrict__ h2b, const float* __restrict__ a_src2,
    const float* __restrict__ a_dst2, const float* __restrict__ bias2,
    float* __restrict__ out, int n) {
  int wave = threadIdx.x >> 6;
  int lane = threadIdx.x & 63;
  int node = blockIdx.x * 4 + wave;
  if (node >= n) return;
  int j = lane >> 3;
  int sub = lane & 7;
  float adst = a_dst2[node];
  int beg = indptr[node], end = indptr[node + 1];
  float acc0 = 0.f, acc1 = 0.f, den = 0.f;
  for (int base = beg; base < end; base += 64) {
    int m = end - base;
    if (m > 64) m = 64;
    int sv = (lane < m) ? (int)csr16[base + lane] : 0;
    for (int p = 0; p < m; p += 8) {
      int s = __shfl(sv, p + j);
      bool act = (p + j) < m;
      float e = a_src2[(unsigned)s] + adst;
      e = (e > 0.f) ? e : 0.2f * e;
      float w = act ? __expf(e) : 0.f;
      den += w;
      unsigned int f = *(const unsigned int*)(h2b + (unsigned)(s * 16 + sub * 2));
      acc0 += w * b2f_lo(f);
      acc1 += w * b2f_hi(f);
    }
  }
#pragma unroll
  for (int o = 8; o < 64; o <<= 1) {
    den  += __shfl_xor(den, o);
    acc0 += __shfl_xor(acc0, o);
    acc1 += __shfl_xor(acc1, o);
  }
  float inv = 1.f / den;
  float v0 = acc0 * inv + bias2[sub * 2];
  float v1 = acc1 * inv + bias2[sub * 2 + 1];
  float mx = fmaxf(v0, v1);
#pragma unroll
  for (int o = 1; o < 8; o <<= 1) mx = fmaxf(mx, __shfl_xor(mx, o));
  float ss = __expf(v0 - mx) + __expf(v1 - mx);
#pragma unroll
  for (int o = 1; o < 8; o <<= 1) ss += __shfl_xor(ss, o);
  float lg = mx + __logf(ss);
  if (j == 0) {
    v2 r;
    r[0] = v0 - lg;
    r[1] = v1 - lg;
    *(v2*)(out + (size_t)node * 16 + sub * 2) = r;
  }
}

// ------------------------------------------------------------------------------
extern "C" void kernel_launch(void* const* d_in, const int* in_sizes, int n_in,
                              void* d_out, int out_size, void* d_ws, size_t ws_size,
                              hipStream_t stream) {
  const float* x        = (const float*)d_in[0];
  const int*   ei       = (const int*)d_in[1];
  const float* W1       = (const float*)d_in[2];
  const float* att_src1 = (const float*)d_in[3];
  const float* att_dst1 = (const float*)d_in[4];
  const float* bias1    = (const float*)d_in[5];
  const float* W2       = (const float*)d_in[6];
  const float* att_src2 = (const float*)d_in[7];
  const float* att_dst2 = (const float*)d_in[8];
  const float* bias2    = (const float*)d_in[9];
  const int* src_idx = ei;
  const int* dst_idx = ei + N_EDGES;

  char* p = (char*)d_ws;
  auto alloc = [&](size_t bytes) {
    void* r = (void*)p;
    p += (bytes + 255) & ~(size_t)255;
    return r;
  };
  unsigned short* h1b = (unsigned short*)alloc((size_t)N_NODES * 64 * 2);
  float* a_src1  = (float*)alloc((size_t)N_NODES * 8 * 4);
  float* a_dst1  = (float*)alloc((size_t)N_NODES * 8 * 4);
  unsigned short* h2b = (unsigned short*)alloc((size_t)N_NODES * 16 * 2);
  float* a_src2  = (float*)alloc((size_t)N_NODES * 4);
  float* a_dst2  = (float*)alloc((size_t)N_NODES * 4);
  int* indptr    = (int*)alloc((size_t)(N_NODES + 1) * 4);
  int* gcur      = (int*)alloc((size_t)NBUCK * 4);
  unsigned short* csr16 = (unsigned short*)alloc((size_t)N_ETOT * 2);
  unsigned short* W1bT  = (unsigned short*)alloc((size_t)64 * F_IN * 2);
  int* abuck     = (int*)alloc((size_t)NBUCK * BCAP * 4);

  w1t_kernel<<<129, 256, 0, stream>>>(W1, W1bT, gcur);
  gemm1_kernel<<<(N_NODES + 63) / 64, 256, 0, stream>>>(
      x, W1bT, att_src1, att_dst1, h1b, a_src1, a_dst1, N_NODES);

  bucketA_kernel<<<(N_EDGES + CHUNKA - 1) / CHUNKA, 256, 0, stream>>>(
      src_idx, dst_idx, gcur, abuck);
  bucketB_kernel<<<NBUCK, 256, 0, stream>>>(gcur, abuck, indptr, csr16);

  agg1_kernel<<<N_NODES / 4, 256, 0, stream>>>(
      indptr, csr16, h1b, a_src1, a_dst1, bias1,
      W2, att_src2, att_dst2, h2b, a_src2, a_dst2, N_NODES);

  agg2_kernel<<<N_NODES / 4, 256, 0, stream>>>(
      indptr, csr16, h2b, a_src2, a_dst2, bias2, (float*)d_out, N_NODES);
}

// Round 7
// 296.782 us; speedup vs baseline: 1.1519x; 1.1519x over previous
//
#include <hip/hip_runtime.h>
#include <cstddef>

#define N_NODES 50000
#define N_EDGES 1600000
#define N_ETOT  (N_EDGES + N_NODES)
#define F_IN    512
#define HEADS   8
#define HID     8
#define CLS     16

#define NBUCK   196      // ceil(50000/256) dst buckets
#define BCAP    12288    // per-bucket capacity
#define CHUNKA  4096     // edges per block in phase A

typedef float v4 __attribute__((ext_vector_type(4)));
typedef float v2 __attribute__((ext_vector_type(2)));
typedef unsigned short us4 __attribute__((ext_vector_type(4)));
typedef unsigned int u4 __attribute__((ext_vector_type(4)));
typedef short bfrag __attribute__((ext_vector_type(8)));   // 8 bf16 = 4 VGPRs
typedef float ffrag __attribute__((ext_vector_type(4)));   // MFMA acc

__device__ inline float b2f_lo(unsigned int u) { return __uint_as_float(u << 16); }
__device__ inline float b2f_hi(unsigned int u) { return __uint_as_float(u & 0xffff0000u); }
__device__ inline v2 up2(unsigned int u) {
  v2 r;
  r[0] = __uint_as_float(u << 16);
  r[1] = __uint_as_float(u & 0xffff0000u);
  return r;
}
__device__ inline unsigned short f2b(float f) {
  unsigned int x = __float_as_uint(f);
  unsigned int r = (x + 0x7fffu + ((x >> 16) & 1u)) >> 16;   // RNE
  return (unsigned short)r;
}

// ---- W1 (512x64 fp32) -> W1bT (64x512 bf16); block 128 zeroes gcur ----------
__global__ __launch_bounds__(256) void w1t_kernel(
    const float* __restrict__ W, unsigned short* __restrict__ WT,
    int* __restrict__ gcur) {
  int t = threadIdx.x;
  if (blockIdx.x == 128) {
    if (t < NBUCK) gcur[t] = 0;
    return;
  }
  int i = blockIdx.x * 256 + t;
  int k = i >> 6, n = i & 63;
  WT[n * F_IN + k] = f2b(W[i]);
}

// ---- GEMM1 (MFMA): x(50000x512 fp32) @ W1 -> h1b(bf16) + attn logits ---------
__global__ __launch_bounds__(256) void gemm1_kernel(
    const float* __restrict__ x, const unsigned short* __restrict__ W1bT,
    const float* __restrict__ att_src, const float* __restrict__ att_dst,
    unsigned short* __restrict__ h1b, float* __restrict__ a_src,
    float* __restrict__ a_dst, int nrows) {
  __shared__ unsigned short xsb[64][72];
  __shared__ unsigned short wsb[64][72];
  int t = threadIdx.x;
  int lane = t & 63;
  int w = t >> 6;
  int row0 = blockIdx.x * 64;
  ffrag acc[4];
  acc[0] = 0.f; acc[1] = 0.f; acc[2] = 0.f; acc[3] = 0.f;

  int mrow = lane & 15;
  int koff = (lane >> 4) * 8;

  for (int kt = 0; kt < 8; ++kt) {
    int k0 = kt * 64;
#pragma unroll
    for (int r = 0; r < 4; ++r) {
      int slot = t + r * 256;
      int m = slot >> 4;
      int k4 = (slot & 15) * 4;
      v4 v = 0.f;
      int grow = row0 + m;
      if (grow < nrows) v = *(const v4*)(x + (size_t)grow * F_IN + k0 + k4);
      us4 o;
      o.x = f2b(v[0]); o.y = f2b(v[1]); o.z = f2b(v[2]); o.w = f2b(v[3]);
      *(us4*)&xsb[m][k4] = o;
    }
#pragma unroll
    for (int r = 0; r < 2; ++r) {
      int slot = t + r * 256;
      int nn = slot >> 3;
      int k8 = (slot & 7) * 8;
      *(bfrag*)&wsb[nn][k8] = *(const bfrag*)(W1bT + nn * F_IN + k0 + k8);
    }
    __syncthreads();
#pragma unroll
    for (int kk = 0; kk < 64; kk += 32) {
      bfrag a = *(const bfrag*)&xsb[w * 16 + mrow][kk + koff];
#pragma unroll
      for (int tt = 0; tt < 4; ++tt) {
        bfrag b = *(const bfrag*)&wsb[tt * 16 + mrow][kk + koff];
        acc[tt] = __builtin_amdgcn_mfma_f32_16x16x32_bf16(a, b, acc[tt], 0, 0, 0);
      }
    }
    __syncthreads();
  }
  int c = lane & 15, q = lane >> 4;
  float as_[4], ad_[4];
#pragma unroll
  for (int tt = 0; tt < 4; ++tt) {
    as_[tt] = att_src[tt * 16 + c];
    ad_[tt] = att_dst[tt * 16 + c];
  }
#pragma unroll
  for (int r = 0; r < 4; ++r) {
    int grow = row0 + w * 16 + q * 4 + r;
    float ps[4], pd[4];
#pragma unroll
    for (int tt = 0; tt < 4; ++tt) {
      ps[tt] = acc[tt][r] * as_[tt];
      pd[tt] = acc[tt][r] * ad_[tt];
    }
#pragma unroll
    for (int o = 1; o < 8; o <<= 1) {
#pragma unroll
      for (int tt = 0; tt < 4; ++tt) {
        ps[tt] += __shfl_xor(ps[tt], o);
        pd[tt] += __shfl_xor(pd[tt], o);
      }
    }
    if (grow < nrows) {
#pragma unroll
      for (int tt = 0; tt < 4; ++tt)
        h1b[(size_t)grow * 64 + tt * 16 + c] = f2b(acc[tt][r]);
      if ((c & 7) == 0) {
#pragma unroll
        for (int tt = 0; tt < 4; ++tt) {
          int head = tt * 2 + (c >> 3);
          a_src[grow * 8 + head] = ps[tt];
          a_dst[grow * 8 + head] = pd[tt];
        }
      }
    }
  }
}

// --------------------------- CSR build (bucketed, 2 kernels) -------------------
__global__ __launch_bounds__(256) void bucketA_kernel(
    const int* __restrict__ src_idx, const int* __restrict__ dst_idx,
    int* __restrict__ gcur, int* __restrict__ abuck) {
  __shared__ int hist[NBUCK];
  __shared__ int base[NBUCK];
  __shared__ int cur[NBUCK];
  int t = threadIdx.x;
  if (t < NBUCK) hist[t] = 0;
  __syncthreads();
  int e0 = blockIdx.x * CHUNKA;
  int eend = e0 + CHUNKA;
  if (eend > N_EDGES) eend = N_EDGES;
  for (int e = e0 + t; e < eend; e += 256)
    atomicAdd(&hist[(unsigned)dst_idx[e] >> 8], 1);
  __syncthreads();
  if (t < NBUCK) {
    int c = hist[t];
    base[t] = c ? atomicAdd(&gcur[t], c) : 0;
    cur[t] = 0;
  }
  __syncthreads();
  for (int e = e0 + t; e < eend; e += 256) {
    int s = src_idx[e];
    int d = dst_idx[e];
    int b = (unsigned)d >> 8;
    int r = atomicAdd(&cur[b], 1);
    abuck[b * BCAP + base[b] + r] = (s << 8) | (d & 255);
  }
}

// Phase B: per-bucket; scans gcur in-block for its base; 16-bit csr out
__global__ __launch_bounds__(256) void bucketB_kernel(
    const int* __restrict__ gcur, const int* __restrict__ abuck,
    int* __restrict__ indptr, unsigned short* __restrict__ csr16) {
  __shared__ int gs[256];
  __shared__ int hist[256];
  __shared__ int sm[256];
  __shared__ int cur[256];
  int b = blockIdx.x;
  int t = threadIdx.x;
  int gv = (t < NBUCK) ? gcur[t] : 0;
  gs[t] = gv;
  __syncthreads();
  for (int o = 1; o < 256; o <<= 1) {
    int u = (t >= o) ? gs[t - o] : 0;
    __syncthreads();
    gs[t] += u;
    __syncthreads();
  }
  int bbase = (b > 0 ? gs[b - 1] : 0) + 256 * b;   // +self-loops of prior buckets
  int M = gcur[b];
  int node0 = b * 256;
  int nnodes = N_NODES - node0;
  if (nnodes > 256) nnodes = 256;
  hist[t] = (t < nnodes) ? 1 : 0;   // self-loop
  __syncthreads();
  const int* ab = abuck + b * BCAP;
  for (int i = t; i < M; i += 256)
    atomicAdd(&hist[ab[i] & 255], 1);
  __syncthreads();
  int v = hist[t];
  sm[t] = v;
  __syncthreads();
  for (int o = 1; o < 256; o <<= 1) {
    int u = (t >= o) ? sm[t - o] : 0;
    __syncthreads();
    sm[t] += u;
    __syncthreads();
  }
  int excl = sm[t] - v;
  cur[t] = excl;
  if (t < nnodes) indptr[node0 + t] = bbase + excl;
  if (b == NBUCK - 1 && t == 0) indptr[N_NODES] = N_ETOT;
  __syncthreads();
  for (int i = t; i < M; i += 256) {
    int entry = ab[i];
    int r = atomicAdd(&cur[entry & 255], 1);
    csr16[bbase + r] = (unsigned short)((unsigned)entry >> 8);
  }
  if (t < nnodes) {
    int r = atomicAdd(&cur[t], 1);
    csr16[bbase + r] = (unsigned short)(node0 + t);
  }
}

// ------------- layer-1 edge softmax + aggregate (16 edges / iter) --------------
// wave = one node; lane = (edge slot j = lane>>3, head h = lane&7)
__global__ __launch_bounds__(256) void agg1_kernel(
    const int* __restrict__ indptr, const unsigned short* __restrict__ csr16,
    const unsigned short* __restrict__ h1b, const float* __restrict__ a_src1,
    const float* __restrict__ a_dst1, const float* __restrict__ bias1,
    float* __restrict__ h_elu, int n) {
  int wave = threadIdx.x >> 6;
  int lane = threadIdx.x & 63;
  int node = blockIdx.x * 4 + wave;
  if (node >= n) return;
  int j = lane >> 3;
  int h = lane & 7;
  float adst = a_dst1[(unsigned)(node * 8 + h)];
  int beg = indptr[node], end = indptr[node + 1];
  v2 acc[4];
  acc[0] = 0.f; acc[1] = 0.f; acc[2] = 0.f; acc[3] = 0.f;
  float den = 0.f;
  for (int base = beg; base < end; base += 64) {
    int m = end - base;
    if (m > 64) m = 64;
    int sv = (lane < m) ? (int)csr16[base + lane] : 0;
    for (int p = 0; p < m; p += 16) {
      int ia = p + j, ib = p + 8 + j;
      int sa = __shfl(sv, ia & 63);
      int sb = __shfl(sv, ib & 63);
      bool aa = ia < m, ab = ib < m;
      // issue all 4 gathers up front (MLP)
      float ga = a_src1[(unsigned)(sa * 8 + h)];
      float gb = a_src1[(unsigned)(sb * 8 + h)];
      u4 fa = *(const u4*)(h1b + (unsigned)(sa * 64 + h * 8));
      u4 fb = *(const u4*)(h1b + (unsigned)(sb * 64 + h * 8));
      float ea = ga + adst, eb = gb + adst;
      ea = fmaxf(ea, 0.2f * ea);          // leaky_relu
      eb = fmaxf(eb, 0.2f * eb);
      float wa = aa ? __expf(ea) : 0.f;
      float wb = ab ? __expf(eb) : 0.f;
      den += wa + wb;
      v2 wa2, wb2;
      wa2[0] = wa; wa2[1] = wa;
      wb2[0] = wb; wb2[1] = wb;
      acc[0] += wa2 * up2(fa.x); acc[1] += wa2 * up2(fa.y);
      acc[2] += wa2 * up2(fa.z); acc[3] += wa2 * up2(fa.w);
      acc[0] += wb2 * up2(fb.x); acc[1] += wb2 * up2(fb.y);
      acc[2] += wb2 * up2(fb.z); acc[3] += wb2 * up2(fb.w);
    }
  }
  // reduce over edge-slot bits (lane bits 3..5)
#pragma unroll
  for (int o = 8; o < 64; o <<= 1) {
    den += __shfl_xor(den, o);
#pragma unroll
    for (int i = 0; i < 4; ++i) {
      acc[i][0] += __shfl_xor(acc[i][0], o);
      acc[i][1] += __shfl_xor(acc[i][1], o);
    }
  }
  if (j == 0) {
    float inv = 1.f / den;
    v4 b0 = *(const v4*)(bias1 + h * 8);
    v4 b1 = *(const v4*)(bias1 + h * 8 + 4);
    v4 o0, o1;
    o0[0] = acc[0][0] * inv + b0[0]; o0[1] = acc[0][1] * inv + b0[1];
    o0[2] = acc[1][0] * inv + b0[2]; o0[3] = acc[1][1] * inv + b0[3];
    o1[0] = acc[2][0] * inv + b1[0]; o1[1] = acc[2][1] * inv + b1[1];
    o1[2] = acc[3][0] * inv + b1[2]; o1[3] = acc[3][1] * inv + b1[3];
#pragma unroll
    for (int k = 0; k < 4; ++k) {
      o0[k] = (o0[k] > 0.f) ? o0[k] : (__expf(o0[k]) - 1.f);   // ELU
      o1[k] = (o1[k] > 0.f) ? o1[k] : (__expf(o1[k]) - 1.f);
    }
    *(v4*)(h_elu + (size_t)node * 64 + h * 8)     = o0;
    *(v4*)(h_elu + (size_t)node * 64 + h * 8 + 4) = o1;
  }
}

// --------- GEMM2: h_elu(50000x64) @ W2(64x16) + attn2 logits epilogue ----------
__global__ __launch_bounds__(256) void gemm2_kernel(
    const float* __restrict__ h_elu, const float* __restrict__ W2,
    const float* __restrict__ att_src2, const float* __restrict__ att_dst2,
    unsigned short* __restrict__ h2b, float* __restrict__ a_src2,
    float* __restrict__ a_dst2, int n) {
  __shared__ float xs[64][68];
  __shared__ float ws[64][16];
  int t = threadIdx.x;
  int row0 = blockIdx.x * 64;
  {
    int k = t >> 2, c4 = (t & 3) * 4;
    *(v4*)&ws[k][c4] = *(const v4*)(W2 + (size_t)k * 16 + c4);
  }
#pragma unroll
  for (int r = 0; r < 4; ++r) {
    int idx = t + r * 256;
    int m = idx >> 4;
    int c4 = (idx & 15) * 4;
    v4 v = 0.f;
    int grow = row0 + m;
    if (grow < n) v = *(const v4*)(h_elu + (size_t)grow * 64 + c4);
    *(v4*)&xs[m][c4] = v;
  }
  __syncthreads();
  int r = t >> 2, q = t & 3;
  int grow = row0 + r;
  v4 acc = 0.f;
#pragma unroll
  for (int k = 0; k < 64; ++k) {
    acc += xs[r][k] * *(const v4*)&ws[k][q * 4];
  }
  v4 asv = *(const v4*)(att_src2 + q * 4);
  v4 adv = *(const v4*)(att_dst2 + q * 4);
  float ps = acc[0] * asv[0] + acc[1] * asv[1] + acc[2] * asv[2] + acc[3] * asv[3];
  float pd = acc[0] * adv[0] + acc[1] * adv[1] + acc[2] * adv[2] + acc[3] * adv[3];
  ps += __shfl_xor(ps, 1); ps += __shfl_xor(ps, 2);
  pd += __shfl_xor(pd, 1); pd += __shfl_xor(pd, 2);
  if (grow < n) {
    us4 o;
    o.x = f2b(acc[0]); o.y = f2b(acc[1]); o.z = f2b(acc[2]); o.w = f2b(acc[3]);
    *(us4*)(h2b + (size_t)grow * 16 + q * 4) = o;
    if (q == 0) { a_src2[grow] = ps; a_dst2[grow] = pd; }
  }
}

// ------- layer-2 aggregate + bias + log_softmax (16 edges / iter) --------------
__global__ __launch_bounds__(256) void agg2_kernel(
    const int* __restrict__ indptr, const unsigned short* __restrict__ csr16,
    const unsigned short* __restrict__ h2b, const float* __restrict__ a_src2,
    const float* __restrict__ a_dst2, const float* __restrict__ bias2,
    float* __restrict__ out, int n) {
  int wave = threadIdx.x >> 6;
  int lane = threadIdx.x & 63;
  int node = blockIdx.x * 4 + wave;
  if (node >= n) return;
  int j = lane >> 3;
  int sub = lane & 7;
  float adst = a_dst2[node];
  int beg = indptr[node], end = indptr[node + 1];
  float acc0 = 0.f, acc1 = 0.f, den = 0.f;
  for (int base = beg; base < end; base += 64) {
    int m = end - base;
    if (m > 64) m = 64;
    int sv = (lane < m) ? (int)csr16[base + lane] : 0;
    for (int p = 0; p < m; p += 16) {
      int ia = p + j, ib = p + 8 + j;
      int sa = __shfl(sv, ia & 63);
      int sb = __shfl(sv, ib & 63);
      bool aa = ia < m, ab = ib < m;
      float ga = a_src2[(unsigned)sa];
      float gb = a_src2[(unsigned)sb];
      unsigned fa = *(const unsigned*)(h2b + (unsigned)(sa * 16 + sub * 2));
      unsigned fb = *(const unsigned*)(h2b + (unsigned)(sb * 16 + sub * 2));
      float ea = ga + adst, eb = gb + adst;
      ea = fmaxf(ea, 0.2f * ea);
      eb = fmaxf(eb, 0.2f * eb);
      float wa = aa ? __expf(ea) : 0.f;
      float wb = ab ? __expf(eb) : 0.f;
      den += wa + wb;
      acc0 += wa * b2f_lo(fa) + wb * b2f_lo(fb);
      acc1 += wa * b2f_hi(fa) + wb * b2f_hi(fb);
    }
  }
#pragma unroll
  for (int o = 8; o < 64; o <<= 1) {
    den  += __shfl_xor(den, o);
    acc0 += __shfl_xor(acc0, o);
    acc1 += __shfl_xor(acc1, o);
  }
  float inv = 1.f / den;
  float v0 = acc0 * inv + bias2[sub * 2];
  float v1 = acc1 * inv + bias2[sub * 2 + 1];
  float mx = fmaxf(v0, v1);
#pragma unroll
  for (int o = 1; o < 8; o <<= 1) mx = fmaxf(mx, __shfl_xor(mx, o));
  float ss = __expf(v0 - mx) + __expf(v1 - mx);
#pragma unroll
  for (int o = 1; o < 8; o <<= 1) ss += __shfl_xor(ss, o);
  float lg = mx + __logf(ss);
  if (j == 0) {
    v2 r;
    r[0] = v0 - lg;
    r[1] = v1 - lg;
    *(v2*)(out + (size_t)node * 16 + sub * 2) = r;
  }
}

// ------------------------------------------------------------------------------
extern "C" void kernel_launch(void* const* d_in, const int* in_sizes, int n_in,
                              void* d_out, int out_size, void* d_ws, size_t ws_size,
                              hipStream_t stream) {
  const float* x        = (const float*)d_in[0];
  const int*   ei       = (const int*)d_in[1];
  const float* W1       = (const float*)d_in[2];
  const float* att_src1 = (const float*)d_in[3];
  const float* att_dst1 = (const float*)d_in[4];
  const float* bias1    = (const float*)d_in[5];
  const float* W2       = (const float*)d_in[6];
  const float* att_src2 = (const float*)d_in[7];
  const float* att_dst2 = (const float*)d_in[8];
  const float* bias2    = (const float*)d_in[9];
  const int* src_idx = ei;
  const int* dst_idx = ei + N_EDGES;

  char* p = (char*)d_ws;
  auto alloc = [&](size_t bytes) {
    void* r = (void*)p;
    p += (bytes + 255) & ~(size_t)255;
    return r;
  };
  unsigned short* h1b = (unsigned short*)alloc((size_t)N_NODES * 64 * 2);
  float* h_elu   = (float*)alloc((size_t)N_NODES * 64 * 4);
  float* a_src1  = (float*)alloc((size_t)N_NODES * 8 * 4);
  float* a_dst1  = (float*)alloc((size_t)N_NODES * 8 * 4);
  unsigned short* h2b = (unsigned short*)alloc((size_t)N_NODES * 16 * 2);
  float* a_src2  = (float*)alloc((size_t)N_NODES * 4);
  float* a_dst2  = (float*)alloc((size_t)N_NODES * 4);
  int* indptr    = (int*)alloc((size_t)(N_NODES + 1) * 4);
  int* gcur      = (int*)alloc((size_t)NBUCK * 4);
  unsigned short* csr16 = (unsigned short*)alloc((size_t)N_ETOT * 2);
  unsigned short* W1bT  = (unsigned short*)alloc((size_t)64 * F_IN * 2);
  // abuck (9.6 MB) aliases h_elu (12.8 MB): build finishes before agg1 writes h_elu
  int* abuck     = (int*)h_elu;

  w1t_kernel<<<129, 256, 0, stream>>>(W1, W1bT, gcur);
  gemm1_kernel<<<(N_NODES + 63) / 64, 256, 0, stream>>>(
      x, W1bT, att_src1, att_dst1, h1b, a_src1, a_dst1, N_NODES);

  bucketA_kernel<<<(N_EDGES + CHUNKA - 1) / CHUNKA, 256, 0, stream>>>(
      src_idx, dst_idx, gcur, abuck);
  bucketB_kernel<<<NBUCK, 256, 0, stream>>>(gcur, abuck, indptr, csr16);

  agg1_kernel<<<N_NODES / 4, 256, 0, stream>>>(
      indptr, csr16, h1b, a_src1, a_dst1, bias1, h_elu, N_NODES);

  gemm2_kernel<<<(N_NODES + 63) / 64, 256, 0, stream>>>(
      h_elu, W2, att_src2, att_dst2, h2b, a_src2, a_dst2, N_NODES);

  agg2_kernel<<<N_NODES / 4, 256, 0, stream>>>(
      indptr, csr16, h2b, a_src2, a_dst2, bias2, (float*)d_out, N_NODES);
}

// Round 8
// 282.697 us; speedup vs baseline: 1.2092x; 1.0498x over previous
//
#include <hip/hip_runtime.h>
#include <cstddef>

#define N_NODES 50000
#define N_EDGES 1600000
#define N_ETOT  (N_EDGES + N_NODES)
#define F_IN    512
#define HEADS   8
#define HID     8
#define CLS     16

#define NBUCK   196      // ceil(50000/256) dst buckets
#define BCAP    12288    // per-bucket capacity
#define CHUNKA  4096     // edges per block in phase A
#define NB_GEMM1 782     // ceil(50000/64)
#define NB_BUCKA 391     // ceil(1600000/4096)

typedef float v4 __attribute__((ext_vector_type(4)));
typedef float v2 __attribute__((ext_vector_type(2)));
typedef unsigned short us4 __attribute__((ext_vector_type(4)));
typedef unsigned int u4 __attribute__((ext_vector_type(4)));
typedef short bfrag __attribute__((ext_vector_type(8)));   // 8 bf16 = 4 VGPRs
typedef float ffrag __attribute__((ext_vector_type(4)));   // MFMA acc

__device__ inline float b2f_lo(unsigned int u) { return __uint_as_float(u << 16); }
__device__ inline float b2f_hi(unsigned int u) { return __uint_as_float(u & 0xffff0000u); }
__device__ inline unsigned short f2b(float f) {
  unsigned int x = __float_as_uint(f);
  unsigned int r = (x + 0x7fffu + ((x >> 16) & 1u)) >> 16;   // RNE
  return (unsigned short)r;
}

// ---- W1 (512x64 fp32) -> W1bT (64x512 bf16); block 128 zeroes gcur ----------
__global__ __launch_bounds__(256) void w1t_kernel(
    const float* __restrict__ W, unsigned short* __restrict__ WT,
    int* __restrict__ gcur) {
  int t = threadIdx.x;
  if (blockIdx.x == 128) {
    if (t < NBUCK) gcur[t] = 0;
    return;
  }
  int i = blockIdx.x * 256 + t;
  int k = i >> 6, n = i & 63;
  WT[n * F_IN + k] = f2b(W[i]);
}

// ---- fused: gemm1 (blocks 0..781) + bucketA (blocks 782..1172) ---------------
__global__ __launch_bounds__(256) void gemm1_bucketA_kernel(
    const float* __restrict__ x, const unsigned short* __restrict__ W1bT,
    const float* __restrict__ att_src, const float* __restrict__ att_dst,
    unsigned short* __restrict__ h1b, float* __restrict__ a_src,
    float* __restrict__ a_dst, int nrows,
    const int* __restrict__ src_idx, const int* __restrict__ dst_idx,
    int* __restrict__ gcur, int* __restrict__ abuck) {
  __shared__ unsigned short xsb[64][72];
  __shared__ unsigned short wsb[64][72];
  __shared__ int hist[NBUCK];
  __shared__ int base[NBUCK];
  __shared__ int cur[NBUCK];
  int t = threadIdx.x;

  if (blockIdx.x >= NB_GEMM1) {
    // ---------------- bucketA ----------------
    if (t < NBUCK) hist[t] = 0;
    __syncthreads();
    int blk = blockIdx.x - NB_GEMM1;
    int e0 = blk * CHUNKA;
    int eend = e0 + CHUNKA;
    if (eend > N_EDGES) eend = N_EDGES;
    for (int e = e0 + t; e < eend; e += 256)
      atomicAdd(&hist[(unsigned)dst_idx[e] >> 8], 1);
    __syncthreads();
    if (t < NBUCK) {
      int c = hist[t];
      base[t] = c ? atomicAdd(&gcur[t], c) : 0;
      cur[t] = 0;
    }
    __syncthreads();
    for (int e = e0 + t; e < eend; e += 256) {
      int s = src_idx[e];
      int d = dst_idx[e];
      int b = (unsigned)d >> 8;
      int r = atomicAdd(&cur[b], 1);
      abuck[b * BCAP + base[b] + r] = (s << 8) | (d & 255);
    }
    return;
  }

  // ---------------- gemm1 (MFMA) ----------------
  int lane = t & 63;
  int w = t >> 6;
  int row0 = blockIdx.x * 64;
  ffrag acc[4];
  acc[0] = 0.f; acc[1] = 0.f; acc[2] = 0.f; acc[3] = 0.f;

  int mrow = lane & 15;
  int koff = (lane >> 4) * 8;

  for (int kt = 0; kt < 8; ++kt) {
    int k0 = kt * 64;
#pragma unroll
    for (int r = 0; r < 4; ++r) {
      int slot = t + r * 256;
      int m = slot >> 4;
      int k4 = (slot & 15) * 4;
      v4 v = 0.f;
      int grow = row0 + m;
      if (grow < nrows) v = *(const v4*)(x + (size_t)grow * F_IN + k0 + k4);
      us4 o;
      o.x = f2b(v[0]); o.y = f2b(v[1]); o.z = f2b(v[2]); o.w = f2b(v[3]);
      *(us4*)&xsb[m][k4] = o;
    }
#pragma unroll
    for (int r = 0; r < 2; ++r) {
      int slot = t + r * 256;
      int nn = slot >> 3;
      int k8 = (slot & 7) * 8;
      *(bfrag*)&wsb[nn][k8] = *(const bfrag*)(W1bT + nn * F_IN + k0 + k8);
    }
    __syncthreads();
#pragma unroll
    for (int kk = 0; kk < 64; kk += 32) {
      bfrag a = *(const bfrag*)&xsb[w * 16 + mrow][kk + koff];
#pragma unroll
      for (int tt = 0; tt < 4; ++tt) {
        bfrag b = *(const bfrag*)&wsb[tt * 16 + mrow][kk + koff];
        acc[tt] = __builtin_amdgcn_mfma_f32_16x16x32_bf16(a, b, acc[tt], 0, 0, 0);
      }
    }
    __syncthreads();
  }
  int c = lane & 15, q = lane >> 4;
  float as_[4], ad_[4];
#pragma unroll
  for (int tt = 0; tt < 4; ++tt) {
    as_[tt] = att_src[tt * 16 + c];
    ad_[tt] = att_dst[tt * 16 + c];
  }
#pragma unroll
  for (int r = 0; r < 4; ++r) {
    int grow = row0 + w * 16 + q * 4 + r;
    float ps[4], pd[4];
#pragma unroll
    for (int tt = 0; tt < 4; ++tt) {
      ps[tt] = acc[tt][r] * as_[tt];
      pd[tt] = acc[tt][r] * ad_[tt];
    }
#pragma unroll
    for (int o = 1; o < 8; o <<= 1) {
#pragma unroll
      for (int tt = 0; tt < 4; ++tt) {
        ps[tt] += __shfl_xor(ps[tt], o);
        pd[tt] += __shfl_xor(pd[tt], o);
      }
    }
    if (grow < nrows) {
#pragma unroll
      for (int tt = 0; tt < 4; ++tt)
        h1b[(size_t)grow * 64 + tt * 16 + c] = f2b(acc[tt][r]);
      if ((c & 7) == 0) {
#pragma unroll
        for (int tt = 0; tt < 4; ++tt) {
          int head = tt * 2 + (c >> 3);
          a_src[grow * 8 + head] = ps[tt];
          a_dst[grow * 8 + head] = pd[tt];
        }
      }
    }
  }
}

// Phase B: per-bucket; scans gcur in-block for its base; 16-bit csr out
__global__ __launch_bounds__(256) void bucketB_kernel(
    const int* __restrict__ gcur, const int* __restrict__ abuck,
    int* __restrict__ indptr, unsigned short* __restrict__ csr16) {
  __shared__ int gs[256];
  __shared__ int hist[256];
  __shared__ int sm[256];
  __shared__ int cur[256];
  int b = blockIdx.x;
  int t = threadIdx.x;
  int gv = (t < NBUCK) ? gcur[t] : 0;
  gs[t] = gv;
  __syncthreads();
  for (int o = 1; o < 256; o <<= 1) {
    int u = (t >= o) ? gs[t - o] : 0;
    __syncthreads();
    gs[t] += u;
    __syncthreads();
  }
  int bbase = (b > 0 ? gs[b - 1] : 0) + 256 * b;   // +self-loops of prior buckets
  int M = gcur[b];
  int node0 = b * 256;
  int nnodes = N_NODES - node0;
  if (nnodes > 256) nnodes = 256;
  hist[t] = (t < nnodes) ? 1 : 0;   // self-loop
  __syncthreads();
  const int* ab = abuck + b * BCAP;
  for (int i = t; i < M; i += 256)
    atomicAdd(&hist[ab[i] & 255], 1);
  __syncthreads();
  int v = hist[t];
  sm[t] = v;
  __syncthreads();
  for (int o = 1; o < 256; o <<= 1) {
    int u = (t >= o) ? sm[t - o] : 0;
    __syncthreads();
    sm[t] += u;
    __syncthreads();
  }
  int excl = sm[t] - v;
  cur[t] = excl;
  if (t < nnodes) indptr[node0 + t] = bbase + excl;
  if (b == NBUCK - 1 && t == 0) indptr[N_NODES] = N_ETOT;
  __syncthreads();
  for (int i = t; i < M; i += 256) {
    int entry = ab[i];
    int r = atomicAdd(&cur[entry & 255], 1);
    csr16[bbase + r] = (unsigned short)((unsigned)entry >> 8);
  }
  if (t < nnodes) {
    int r = atomicAdd(&cur[t], 1);
    csr16[bbase + r] = (unsigned short)(node0 + t);
  }
}

// ------------- layer-1 edge softmax + aggregate (32 edges / iter) --------------
// wave = one node; lane = (edge slot j = lane>>3, head h = lane&7)
__global__ __launch_bounds__(256) void agg1_kernel(
    const int* __restrict__ indptr, const unsigned short* __restrict__ csr16,
    const unsigned short* __restrict__ h1b, const float* __restrict__ a_src1,
    const float* __restrict__ a_dst1, const float* __restrict__ bias1,
    float* __restrict__ h_elu, int n) {
  int wave = threadIdx.x >> 6;
  int lane = threadIdx.x & 63;
  int node = blockIdx.x * 4 + wave;
  if (node >= n) return;
  int j = lane >> 3;
  int h = lane & 7;
  float adst = a_dst1[(unsigned)(node * 8 + h)];
  int beg = indptr[node], end = indptr[node + 1];
  v2 acc[4];
  acc[0] = 0.f; acc[1] = 0.f; acc[2] = 0.f; acc[3] = 0.f;
  float den = 0.f;
  for (int base = beg; base < end; base += 64) {
    int m = end - base;
    if (m > 64) m = 64;
    int sv = (lane < m) ? (int)csr16[base + lane] : 0;
    for (int p = 0; p < m; p += 32) {
      int i0 = p + j, i1 = p + 8 + j, i2 = p + 16 + j, i3 = p + 24 + j;
      int s0 = __shfl(sv, i0);
      int s1 = __shfl(sv, i1);
      int s2 = __shfl(sv, i2);
      int s3 = __shfl(sv, i3);
      bool a0 = i0 < m, a1 = i1 < m, a2 = i2 < m, a3 = i3 < m;
      // 8 independent gathers in flight
      float g0 = a_src1[(unsigned)(s0 * 8 + h)];
      float g1 = a_src1[(unsigned)(s1 * 8 + h)];
      float g2 = a_src1[(unsigned)(s2 * 8 + h)];
      float g3 = a_src1[(unsigned)(s3 * 8 + h)];
      u4 f0 = *(const u4*)(h1b + (unsigned)(s0 * 64 + h * 8));
      u4 f1 = *(const u4*)(h1b + (unsigned)(s1 * 64 + h * 8));
      u4 f2 = *(const u4*)(h1b + (unsigned)(s2 * 64 + h * 8));
      u4 f3 = *(const u4*)(h1b + (unsigned)(s3 * 64 + h * 8));
      float e0 = g0 + adst, e1 = g1 + adst, e2 = g2 + adst, e3 = g3 + adst;
      e0 = fmaxf(e0, 0.2f * e0); e1 = fmaxf(e1, 0.2f * e1);
      e2 = fmaxf(e2, 0.2f * e2); e3 = fmaxf(e3, 0.2f * e3);
      float w0 = a0 ? __expf(e0) : 0.f;
      float w1 = a1 ? __expf(e1) : 0.f;
      float w2 = a2 ? __expf(e2) : 0.f;
      float w3 = a3 ? __expf(e3) : 0.f;
      den += (w0 + w1) + (w2 + w3);
      v2 w0v, w1v, w2v, w3v;
      w0v[0] = w0; w0v[1] = w0;
      w1v[0] = w1; w1v[1] = w1;
      w2v[0] = w2; w2v[1] = w2;
      w3v[0] = w3; w3v[1] = w3;
      v2 t0, t1, t2, t3;
      t0[0] = b2f_lo(f0.x); t0[1] = b2f_hi(f0.x);
      t1[0] = b2f_lo(f1.x); t1[1] = b2f_hi(f1.x);
      t2[0] = b2f_lo(f2.x); t2[1] = b2f_hi(f2.x);
      t3[0] = b2f_lo(f3.x); t3[1] = b2f_hi(f3.x);
      acc[0] += w0v * t0 + w1v * t1 + w2v * t2 + w3v * t3;
      t0[0] = b2f_lo(f0.y); t0[1] = b2f_hi(f0.y);
      t1[0] = b2f_lo(f1.y); t1[1] = b2f_hi(f1.y);
      t2[0] = b2f_lo(f2.y); t2[1] = b2f_hi(f2.y);
      t3[0] = b2f_lo(f3.y); t3[1] = b2f_hi(f3.y);
      acc[1] += w0v * t0 + w1v * t1 + w2v * t2 + w3v * t3;
      t0[0] = b2f_lo(f0.z); t0[1] = b2f_hi(f0.z);
      t1[0] = b2f_lo(f1.z); t1[1] = b2f_hi(f1.z);
      t2[0] = b2f_lo(f2.z); t2[1] = b2f_hi(f2.z);
      t3[0] = b2f_lo(f3.z); t3[1] = b2f_hi(f3.z);
      acc[2] += w0v * t0 + w1v * t1 + w2v * t2 + w3v * t3;
      t0[0] = b2f_lo(f0.w); t0[1] = b2f_hi(f0.w);
      t1[0] = b2f_lo(f1.w); t1[1] = b2f_hi(f1.w);
      t2[0] = b2f_lo(f2.w); t2[1] = b2f_hi(f2.w);
      t3[0] = b2f_lo(f3.w); t3[1] = b2f_hi(f3.w);
      acc[3] += w0v * t0 + w1v * t1 + w2v * t2 + w3v * t3;
    }
  }
  // reduce over edge-slot bits (lane bits 3..5)
#pragma unroll
  for (int o = 8; o < 64; o <<= 1) {
    den += __shfl_xor(den, o);
#pragma unroll
    for (int i = 0; i < 4; ++i) {
      acc[i][0] += __shfl_xor(acc[i][0], o);
      acc[i][1] += __shfl_xor(acc[i][1], o);
    }
  }
  if (j == 0) {
    float inv = 1.f / den;
    v4 b0 = *(const v4*)(bias1 + h * 8);
    v4 b1 = *(const v4*)(bias1 + h * 8 + 4);
    v4 o0, o1;
    o0[0] = acc[0][0] * inv + b0[0]; o0[1] = acc[0][1] * inv + b0[1];
    o0[2] = acc[1][0] * inv + b0[2]; o0[3] = acc[1][1] * inv + b0[3];
    o1[0] = acc[2][0] * inv + b1[0]; o1[1] = acc[2][1] * inv + b1[1];
    o1[2] = acc[3][0] * inv + b1[2]; o1[3] = acc[3][1] * inv + b1[3];
#pragma unroll
    for (int k = 0; k < 4; ++k) {
      o0[k] = (o0[k] > 0.f) ? o0[k] : (__expf(o0[k]) - 1.f);   // ELU
      o1[k] = (o1[k] > 0.f) ? o1[k] : (__expf(o1[k]) - 1.f);
    }
    *(v4*)(h_elu + (size_t)node * 64 + h * 8)     = o0;
    *(v4*)(h_elu + (size_t)node * 64 + h * 8 + 4) = o1;
  }
}

// --------- GEMM2: h_elu(50000x64) @ W2(64x16) + attn2 logits epilogue ----------
__global__ __launch_bounds__(256) void gemm2_kernel(
    const float* __restrict__ h_elu, const float* __restrict__ W2,
    const float* __restrict__ att_src2, const float* __restrict__ att_dst2,
    unsigned short* __restrict__ h2b, float* __restrict__ a_src2,
    float* __restrict__ a_dst2, int n) {
  __shared__ float xs[64][68];
  __shared__ float ws[64][16];
  int t = threadIdx.x;
  int row0 = blockIdx.x * 64;
  {
    int k = t >> 2, c4 = (t & 3) * 4;
    *(v4*)&ws[k][c4] = *(const v4*)(W2 + (size_t)k * 16 + c4);
  }
#pragma unroll
  for (int r = 0; r < 4; ++r) {
    int idx = t + r * 256;
    int m = idx >> 4;
    int c4 = (idx & 15) * 4;
    v4 v = 0.f;
    int grow = row0 + m;
    if (grow < n) v = *(const v4*)(h_elu + (size_t)grow * 64 + c4);
    *(v4*)&xs[m][c4] = v;
  }
  __syncthreads();
  int r = t >> 2, q = t & 3;
  int grow = row0 + r;
  v4 acc = 0.f;
#pragma unroll
  for (int k = 0; k < 64; ++k) {
    acc += xs[r][k] * *(const v4*)&ws[k][q * 4];
  }
  v4 asv = *(const v4*)(att_src2 + q * 4);
  v4 adv = *(const v4*)(att_dst2 + q * 4);
  float ps = acc[0] * asv[0] + acc[1] * asv[1] + acc[2] * asv[2] + acc[3] * asv[3];
  float pd = acc[0] * adv[0] + acc[1] * adv[1] + acc[2] * adv[2] + acc[3] * adv[3];
  ps += __shfl_xor(ps, 1); ps += __shfl_xor(ps, 2);
  pd += __shfl_xor(pd, 1); pd += __shfl_xor(pd, 2);
  if (grow < n) {
    us4 o;
    o.x = f2b(acc[0]); o.y = f2b(acc[1]); o.z = f2b(acc[2]); o.w = f2b(acc[3]);
    *(us4*)(h2b + (size_t)grow * 16 + q * 4) = o;
    if (q == 0) { a_src2[grow] = ps; a_dst2[grow] = pd; }
  }
}

// ------- layer-2 aggregate + bias + log_softmax (32 edges / iter) --------------
__global__ __launch_bounds__(256) void agg2_kernel(
    const int* __restrict__ indptr, const unsigned short* __restrict__ csr16,
    const unsigned short* __restrict__ h2b, const float* __restrict__ a_src2,
    const float* __restrict__ a_dst2, const float* __restrict__ bias2,
    float* __restrict__ out, int n) {
  int wave = threadIdx.x >> 6;
  int lane = threadIdx.x & 63;
  int node = blockIdx.x * 4 + wave;
  if (node >= n) return;
  int j = lane >> 3;
  int sub = lane & 7;
  float adst = a_dst2[node];
  int beg = indptr[node], end = indptr[node + 1];
  float acc0 = 0.f, acc1 = 0.f, den = 0.f;
  for (int base = beg; base < end; base += 64) {
    int m = end - base;
    if (m > 64) m = 64;
    int sv = (lane < m) ? (int)csr16[base + lane] : 0;
    for (int p = 0; p < m; p += 32) {
      int i0 = p + j, i1 = p + 8 + j, i2 = p + 16 + j, i3 = p + 24 + j;
      int s0 = __shfl(sv, i0);
      int s1 = __shfl(sv, i1);
      int s2 = __shfl(sv, i2);
      int s3 = __shfl(sv, i3);
      bool a0 = i0 < m, a1 = i1 < m, a2 = i2 < m, a3 = i3 < m;
      float g0 = a_src2[(unsigned)s0];
      float g1 = a_src2[(unsigned)s1];
      float g2 = a_src2[(unsigned)s2];
      float g3 = a_src2[(unsigned)s3];
      unsigned f0 = *(const unsigned*)(h2b + (unsigned)(s0 * 16 + sub * 2));
      unsigned f1 = *(const unsigned*)(h2b + (unsigned)(s1 * 16 + sub * 2));
      unsigned f2 = *(const unsigned*)(h2b + (unsigned)(s2 * 16 + sub * 2));
      unsigned f3 = *(const unsigned*)(h2b + (unsigned)(s3 * 16 + sub * 2));
      float e0 = g0 + adst, e1 = g1 + adst, e2 = g2 + adst, e3 = g3 + adst;
      e0 = fmaxf(e0, 0.2f * e0); e1 = fmaxf(e1, 0.2f * e1);
      e2 = fmaxf(e2, 0.2f * e2); e3 = fmaxf(e3, 0.2f * e3);
      float w0 = a0 ? __expf(e0) : 0.f;
      float w1 = a1 ? __expf(e1) : 0.f;
      float w2 = a2 ? __expf(e2) : 0.f;
      float w3 = a3 ? __expf(e3) : 0.f;
      den += (w0 + w1) + (w2 + w3);
      acc0 += w0 * b2f_lo(f0) + w1 * b2f_lo(f1) + w2 * b2f_lo(f2) + w3 * b2f_lo(f3);
      acc1 += w0 * b2f_hi(f0) + w1 * b2f_hi(f1) + w2 * b2f_hi(f2) + w3 * b2f_hi(f3);
    }
  }
#pragma unroll
  for (int o = 8; o < 64; o <<= 1) {
    den  += __shfl_xor(den, o);
    acc0 += __shfl_xor(acc0, o);
    acc1 += __shfl_xor(acc1, o);
  }
  float inv = 1.f / den;
  float v0 = acc0 * inv + bias2[sub * 2];
  float v1 = acc1 * inv + bias2[sub * 2 + 1];
  float mx = fmaxf(v0, v1);
#pragma unroll
  for (int o = 1; o < 8; o <<= 1) mx = fmaxf(mx, __shfl_xor(mx, o));
  float ss = __expf(v0 - mx) + __expf(v1 - mx);
#pragma unroll
  for (int o = 1; o < 8; o <<= 1) ss += __shfl_xor(ss, o);
  float lg = mx + __logf(ss);
  if (j == 0) {
    v2 r;
    r[0] = v0 - lg;
    r[1] = v1 - lg;
    *(v2*)(out + (size_t)node * 16 + sub * 2) = r;
  }
}

// ------------------------------------------------------------------------------
extern "C" void kernel_launch(void* const* d_in, const int* in_sizes, int n_in,
                              void* d_out, int out_size, void* d_ws, size_t ws_size,
                              hipStream_t stream) {
  const float* x        = (const float*)d_in[0];
  const int*   ei       = (const int*)d_in[1];
  const float* W1       = (const float*)d_in[2];
  const float* att_src1 = (const float*)d_in[3];
  const float* att_dst1 = (const float*)d_in[4];
  const float* bias1    = (const float*)d_in[5];
  const float* W2       = (const float*)d_in[6];
  const float* att_src2 = (const float*)d_in[7];
  const float* att_dst2 = (const float*)d_in[8];
  const float* bias2    = (const float*)d_in[9];
  const int* src_idx = ei;
  const int* dst_idx = ei + N_EDGES;

  char* p = (char*)d_ws;
  auto alloc = [&](size_t bytes) {
    void* r = (void*)p;
    p += (bytes + 255) & ~(size_t)255;
    return r;
  };
  unsigned short* h1b = (unsigned short*)alloc((size_t)N_NODES * 64 * 2);
  float* h_elu   = (float*)alloc((size_t)N_NODES * 64 * 4);
  float* a_src1  = (float*)alloc((size_t)N_NODES * 8 * 4);
  float* a_dst1  = (float*)alloc((size_t)N_NODES * 8 * 4);
  unsigned short* h2b = (unsigned short*)alloc((size_t)N_NODES * 16 * 2);
  float* a_src2  = (float*)alloc((size_t)N_NODES * 4);
  float* a_dst2  = (float*)alloc((size_t)N_NODES * 4);
  int* indptr    = (int*)alloc((size_t)(N_NODES + 1) * 4);
  int* gcur      = (int*)alloc((size_t)NBUCK * 4);
  unsigned short* csr16 = (unsigned short*)alloc((size_t)N_ETOT * 2);
  unsigned short* W1bT  = (unsigned short*)alloc((size_t)64 * F_IN * 2);
  // abuck (9.6 MB) aliases h_elu (12.8 MB): build finishes before agg1 writes h_elu
  int* abuck     = (int*)h_elu;

  w1t_kernel<<<129, 256, 0, stream>>>(W1, W1bT, gcur);

  gemm1_bucketA_kernel<<<NB_GEMM1 + NB_BUCKA, 256, 0, stream>>>(
      x, W1bT, att_src1, att_dst1, h1b, a_src1, a_dst1, N_NODES,
      src_idx, dst_idx, gcur, abuck);

  bucketB_kernel<<<NBUCK, 256, 0, stream>>>(gcur, abuck, indptr, csr16);

  agg1_kernel<<<N_NODES / 4, 256, 0, stream>>>(
      indptr, csr16, h1b, a_src1, a_dst1, bias1, h_elu, N_NODES);

  gemm2_kernel<<<(N_NODES + 63) / 64, 256, 0, stream>>>(
      h_elu, W2, att_src2, att_dst2, h2b, a_src2, a_dst2, N_NODES);

  agg2_kernel<<<N_NODES / 4, 256, 0, stream>>>(
      indptr, csr16, h2b, a_src2, a_dst2, bias2, (float*)d_out, N_NODES);
}